// Round 6
// baseline (3984.406 us; speedup 1.0000x reference)
//
#include <hip/hip_runtime.h>
#include <hip/hip_bf16.h>

// Problem constants: N=64, C=64, T=128, V=25, H=3, DQ=32
// Inputs: float32. Output: float32 (compared under bf16-floored threshold).

#define WS_ATT   0         // 120000 floats: att accumulator, then final att
#define WS_STATS 120000    // 128 floats: per-channel sum, sumsq
#define WS_WBF   120128    // 30720 floats-worth = 61440 bf16: Wout as [tap][o][hc]

typedef __attribute__((ext_vector_type(8))) short short8;   // 8 bf16 (4 VGPRs)
typedef __attribute__((ext_vector_type(4))) float floatx4;  // MFMA acc

__device__ __forceinline__ float us2f(unsigned short u) {
    union { unsigned int i; float f; } w; w.i = ((unsigned int)u) << 16; return w.f;
}
__device__ __forceinline__ unsigned short f2us(float f) {
    __hip_bfloat16_raw r = __float2bfloat16(f); return r.x;
}

// ---------------------------------------------------------------------------
// K0: reorder Wout [o=64][I=192][tap=5] fp32 -> Abf [tap][o][hc] bf16 (ws).
// ---------------------------------------------------------------------------
__global__ void k_wprep(const float* __restrict__ Wout, unsigned short* __restrict__ Abf)
{
    int i = blockIdx.x * 256 + threadIdx.x;
    if (i >= 61440) return;
    int tap = i / 12288, rem = i % 12288;
    int o = rem / 192, hc = rem % 192;
    Abf[i] = f2us(Wout[o * 960 + hc * 5 + tap]);
}

// ---------------------------------------------------------------------------
// K1: att_raw accumulation (unchanged from R5).
// ---------------------------------------------------------------------------
__global__ __launch_bounds__(256) void k_att(
    const float* __restrict__ x, const float* __restrict__ Wqkv,
    const float* __restrict__ bqkv, float* __restrict__ att_raw)
{
    __shared__ float wq_s[2048], wk_s[2048];
    __shared__ float bq_s[32], bk_s[32];
    __shared__ float pe_s[1600];
    __shared__ float xs_s[3400];
    __shared__ float q_s[1600], k_s[1600];

    const int tid = threadIdx.x;
    const int tblk = blockIdx.x;
    const int h = blockIdx.y, n = blockIdx.z;

    for (int e = tid; e < 2048; e += 256) {
        int cp = e >> 6, c = e & 63;
        wq_s[e] = Wqkv[(h * 32 + cp) * 64 + c];
        wk_s[e] = Wqkv[(96 + h * 32 + cp) * 64 + c];
    }
    if (tid < 32) {
        bq_s[tid] = bqkv[h * 32 + tid];
        bk_s[tid] = bqkv[96 + h * 32 + tid];
    }
    for (int e = tid; e < 1600; e += 256) {
        int c = e / 25, v = e % 25;
        int i = c >> 1;
        float d = expf(-(float)(2 * i) * (9.210340371976184f / 64.0f));
        float a = (float)v * d;
        pe_s[e] = (c & 1) ? cosf(a) : sinf(a);
    }

    float racc[3] = {0.0f, 0.0f, 0.0f};

    for (int chunk = 0; chunk < 8; ++chunk) {
        const int t0 = tblk * 16 + chunk * 2;
        __syncthreads();
        for (int e = tid; e < 3200; e += 256) {
            int c = e / 50, j = e % 50;
            int tl = j / 25, v = j % 25;
            xs_s[j * 68 + c] =
                x[((n * 64 + c) * 128 + t0 + tl) * 25 + v] + pe_s[c * 25 + v];
        }
        __syncthreads();
        for (int e = tid; e < 1600; e += 256) {
            int row = e / 50, j = e % 50;
            float aq = bq_s[row], ak = bk_s[row];
            const float* wqr = &wq_s[row * 64];
            const float* wkr = &wk_s[row * 64];
            const float* xr  = &xs_s[j * 68];
            #pragma unroll 8
            for (int c = 0; c < 64; ++c) {
                float xv = xr[c];
                aq = fmaf(wqr[c], xv, aq);
                ak = fmaf(wkr[c], xv, ak);
            }
            q_s[e] = aq; k_s[e] = ak;
        }
        __syncthreads();
        #pragma unroll
        for (int s = 0; s < 3; ++s) {
            int p = tid + s * 256;
            if (p < 625) {
                int u = p / 25, v = p % 25;
                float acc = racc[s];
                for (int cp = 0; cp < 32; ++cp) {
                    const float* qr = &q_s[cp * 50];
                    const float* kr = &k_s[cp * 50];
                    acc = fmaf(qr[u],      kr[v],      acc);
                    acc = fmaf(qr[25 + u], kr[25 + v], acc);
                }
                racc[s] = acc;
            }
        }
    }

    #pragma unroll
    for (int s = 0; s < 3; ++s) {
        int p = tid + s * 256;
        if (p < 625)
            atomicAdd(&att_raw[(n * 3 + h) * 625 + p], racc[s]);
    }
}

// ---------------------------------------------------------------------------
// K1b: att = tanh(att_raw/4096)*alpha[h] + att0[h,u,v]  (in place)
// ---------------------------------------------------------------------------
__global__ void k_attfin(float* __restrict__ att, const float* __restrict__ alphas,
                         const float* __restrict__ att0s)
{
    int idx = blockIdx.x * 256 + threadIdx.x;
    if (idx >= 64 * 3 * 625) return;
    int nh = idx / 625, p = idx % 625;
    int h = nh % 3;
    float a = att[idx];
    att[idx] = tanhf(a * (1.0f / 4096.0f)) * alphas[h] + att0s[h * 625 + p];
}

// ---------------------------------------------------------------------------
// K2: MFMA implicit-GEMM conv.
// out[o,(t,v)] = sum_{tap,hc} A[tap][o][hc] * yT[t][v+tap][hc]  (+bias)
// Block = (4-frame tile, n). yT bf16 in LDS, XOR-swizzled (hcb ^ (vv&7)).
// 4 waves: (mgrp = M-half of 32 o's) x (ngrp = N-group of cols).
// MFMA 16x16x32 bf16; frags: A/B [m|n=lane&15][k=quad*8+j], C col=lane&15,
// row=quad*4+reg (m89/m92-verified layouts).
// ---------------------------------------------------------------------------
__global__ __launch_bounds__(256) void k_conv(
    const float* __restrict__ x, const unsigned short* __restrict__ Abf,
    const float* __restrict__ bout, const float* __restrict__ att,
    float* __restrict__ out)
{
    __shared__ unsigned short yT[22272];   // [t(4)][vv(29)][hc(192)] bf16, swizzled
    __shared__ unsigned short x_sb[6400];  // [c(64)][t(4)][u(25)] bf16
    __shared__ float att_s[1875];          // [h][u][v]

    const int tid = threadIdx.x;
    const int n = blockIdx.y;
    const int t0 = blockIdx.x * 4;

    // ---- stage x (bf16), att (fp32), zero halo rows of yT ----
    for (int e = tid; e < 6400; e += 256) {
        int c = e / 100, r = e % 100;
        x_sb[e] = f2us(x[(size_t)(n * 64 + c) * 3200 + t0 * 25 + r]);
    }
    for (int e = tid; e < 1875; e += 256) att_s[e] = att[n * 1875 + e];
    for (int e = tid; e < 3072; e += 256) {
        int t = e / 768, r = e % 768;
        int vi = r / 192, hc = r % 192;
        int vv = (vi < 2) ? vi : (25 + vi);          // {0,1,27,28}
        int phys = (t * 29 + vv) * 192 + (((hc >> 3) ^ (vv & 7)) << 3) + (hc & 7);
        yT[phys] = 0;
    }
    __syncthreads();

    // ---- build y tile: y[hc][t][v] = sum_u x[c,t,u] att[h,u,v], 2 hc per thread ----
    for (int e = tid; e < 9600; e += 256) {
        int col = e / 96, hcp = e % 96;
        int hc = hcp * 2;
        int t = col / 25, v = col % 25;
        int h = hc >> 6, c = hc & 63;
        const unsigned short* xr0 = &x_sb[c * 100 + t * 25];
        const unsigned short* xr1 = xr0 + 100;
        const float* ar = &att_s[h * 625 + v];       // stride 25 over u
        float y0 = 0.0f, y1 = 0.0f;
        #pragma unroll
        for (int u = 0; u < 25; ++u) {
            float a = ar[u * 25];
            y0 = fmaf(us2f(xr0[u]), a, y0);
            y1 = fmaf(us2f(xr1[u]), a, y1);
        }
        int vv = v + 2;
        int phys = (t * 29 + vv) * 192 + (((hc >> 3) ^ (vv & 7)) << 3) + (hc & 7);
        unsigned int pk = (unsigned int)f2us(y0) | ((unsigned int)f2us(y1) << 16);
        *(unsigned int*)&yT[phys] = pk;
    }
    __syncthreads();

    // ---- MFMA GEMM: M=64(o) x N=100(cols) x K=960(tap*192+hc) ----
    const int lane = tid & 63, wv = tid >> 6;
    const int quad = lane >> 4, l16 = lane & 15;
    const int mgrp = wv >> 1, ngrp = wv & 1;
    const int m0 = mgrp * 32;
    const int NT = ngrp ? 3 : 4;
    const int nbase = ngrp * 64;

    floatx4 acc[2][4];
    #pragma unroll
    for (int mt = 0; mt < 2; ++mt)
        #pragma unroll
        for (int nt = 0; nt < 4; ++nt)
            acc[mt][nt] = (floatx4){0.f, 0.f, 0.f, 0.f};

    int tcol[4], vcol[4];
    #pragma unroll
    for (int nt = 0; nt < 4; ++nt) {
        int col = nbase + nt * 16 + l16;
        if (col > 99) col = 99;                      // clamp; store is masked
        tcol[nt] = col / 25; vcol[nt] = col % 25;
    }
    const unsigned short* ap0 = Abf + (m0 + l16) * 192 + quad * 8;
    const unsigned short* ap1 = ap0 + 16 * 192;

    for (int tap = 0; tap < 5; ++tap) {
        int rowoff[4], vx[4];
        #pragma unroll
        for (int nt = 0; nt < 4; ++nt) {
            int vv = vcol[nt] + tap;
            rowoff[nt] = (tcol[nt] * 29 + vv) * 192;
            vx[nt] = vv & 7;
        }
        #pragma unroll
        for (int kk = 0; kk < 6; ++kk) {
            const int koff = tap * 12288 + kk * 32;
            short8 a0 = *(const short8*)(ap0 + koff);
            short8 a1 = *(const short8*)(ap1 + koff);
            const int hcb = kk * 4 + quad;
            short8 b[4];
            for (int nt = 0; nt < NT; ++nt) {
                int phys = rowoff[nt] + ((hcb ^ vx[nt]) << 3);
                b[nt] = *(const short8*)&yT[phys];
            }
            for (int nt = 0; nt < NT; ++nt) {
                acc[0][nt] = __builtin_amdgcn_mfma_f32_16x16x32_bf16(a0, b[nt], acc[0][nt], 0, 0, 0);
                acc[1][nt] = __builtin_amdgcn_mfma_f32_16x16x32_bf16(a1, b[nt], acc[1][nt], 0, 0, 0);
            }
        }
    }

    // ---- epilogue: C frag (col=lane&15, row=quad*4+reg) -> out + bias ----
    #pragma unroll
    for (int mt = 0; mt < 2; ++mt) {
        int obase = m0 + mt * 16 + quad * 4;
        for (int nt = 0; nt < NT; ++nt) {
            int col = nbase + nt * 16 + l16;
            if (col < 100) {
                int t = col / 25, v = col % 25;
                #pragma unroll
                for (int reg = 0; reg < 4; ++reg) {
                    int o = obase + reg;
                    out[(size_t)(n * 64 + o) * 3200 + (t0 + t) * 25 + v]
                        = acc[mt][nt][reg] + bout[o];
                }
            }
        }
    }
}

// ---------------------------------------------------------------------------
// K3: per-channel sum/sumsq of conv output (fp32, staged in d_out).
// ---------------------------------------------------------------------------
__global__ __launch_bounds__(256) void k_stats(const float* __restrict__ conv,
                                               float* __restrict__ stats)
{
    const int o = blockIdx.x;
    const int tid = threadIdx.x;
    float s1 = 0.0f, s2 = 0.0f;
    for (int e = tid; e < 64 * 3200; e += 256) {
        int nn = e / 3200, i = e % 3200;
        float v = conv[(size_t)(nn * 64 + o) * 3200 + i];
        s1 += v; s2 = fmaf(v, v, s2);
    }
    for (int off = 32; off > 0; off >>= 1) {
        s1 += __shfl_down(s1, off);
        s2 += __shfl_down(s2, off);
    }
    __shared__ float r1[4], r2[4];
    int w = tid >> 6;
    if ((tid & 63) == 0) { r1[w] = s1; r2[w] = s2; }
    __syncthreads();
    if (tid == 0) {
        stats[o]      = r1[0] + r1[1] + r1[2] + r1[3];
        stats[64 + o] = r2[0] + r2[1] + r2[2] + r2[3];
    }
}

// ---------------------------------------------------------------------------
// K4: out = leaky_relu( BN(conv) + x ), in place over d_out.
// ---------------------------------------------------------------------------
__global__ void k_final(const float* __restrict__ stats, const float* __restrict__ x,
                        const float* __restrict__ gamma, const float* __restrict__ beta,
                        float* __restrict__ out)
{
    size_t idx = (size_t)blockIdx.x * 256 + threadIdx.x;
    if (idx >= (size_t)13107200) return;
    int o = (int)((idx / 3200) & 63);
    const float inv = 1.0f / 204800.0f;
    float m   = stats[o] * inv;
    float ex2 = stats[64 + o] * inv;
    float var = ex2 - m * m;
    float r = rsqrtf(var + 1e-5f);
    float v = out[idx];
    float val = (v - m) * r * gamma[o] + beta[o] + x[idx];
    val = fmaxf(val, 0.1f * val);
    out[idx] = val;
}

// ---------------------------------------------------------------------------
extern "C" void kernel_launch(void* const* d_in, const int* in_sizes, int n_in,
                              void* d_out, int out_size, void* d_ws, size_t ws_size,
                              hipStream_t stream)
{
    const float* x      = (const float*)d_in[0];
    const float* Wqkv   = (const float*)d_in[1];
    const float* bqkv   = (const float*)d_in[2];
    const float* alphas = (const float*)d_in[3];
    const float* att0s  = (const float*)d_in[4];
    const float* Wout   = (const float*)d_in[5];
    const float* bout   = (const float*)d_in[6];
    const float* gamma  = (const float*)d_in[7];
    const float* beta   = (const float*)d_in[8];
    float* ws  = (float*)d_ws;
    float* out = (float*)d_out;
    unsigned short* Abf = (unsigned short*)(ws + WS_WBF);

    hipMemsetAsync(d_ws, 0, (size_t)120000 * sizeof(float), stream);

    k_wprep <<<240, 256, 0, stream>>>(Wout, Abf);
    k_att   <<<dim3(8, 3, 64), 256, 0, stream>>>(x, Wqkv, bqkv, ws + WS_ATT);
    k_attfin<<<(120000 + 255) / 256, 256, 0, stream>>>(ws + WS_ATT, alphas, att0s);
    k_conv  <<<dim3(32, 64),   256, 0, stream>>>(x, Abf, bout, ws + WS_ATT, out);
    k_stats <<<64,             256, 0, stream>>>(out, ws + WS_STATS);
    k_final <<<51200,          256, 0, stream>>>(ws + WS_STATS, x, gamma, beta, out);
}

// Round 7
// 919.576 us; speedup vs baseline: 4.3329x; 4.3329x over previous
//
#include <hip/hip_runtime.h>
#include <hip/hip_bf16.h>

// Problem constants: N=64, C=64, T=128, V=25, H=3, DQ=32
// Inputs: float32. Output: float32 (compared under bf16-floored threshold).

#define WS_ATT   0         // 120000 floats: att accumulator, then final att
#define WS_STATS 120000    // 128 floats: per-channel sum, sumsq
#define WS_WBF   120128    // 30720 floats-worth = 61440 bf16: Wout as [tap][o][hc]

typedef __attribute__((ext_vector_type(8))) short short8;   // 8 bf16 (4 VGPRs)
typedef __attribute__((ext_vector_type(4))) float floatx4;  // MFMA acc

__device__ __forceinline__ float us2f(unsigned short u) {
    union { unsigned int i; float f; } w; w.i = ((unsigned int)u) << 16; return w.f;
}
__device__ __forceinline__ unsigned short f2us(float f) {
    __hip_bfloat16_raw r = __float2bfloat16(f); return r.x;
}

// ---------------------------------------------------------------------------
// K0: reorder Wout [o=64][I=192][tap=5] fp32 -> Abf [tap][o][hc] bf16 (ws).
// ---------------------------------------------------------------------------
__global__ void k_wprep(const float* __restrict__ Wout, unsigned short* __restrict__ Abf)
{
    int i = blockIdx.x * 256 + threadIdx.x;
    if (i >= 61440) return;
    int tap = i / 12288, rem = i % 12288;
    int o = rem / 192, hc = rem % 192;
    Abf[i] = f2us(Wout[o * 960 + hc * 5 + tap]);
}

// ---------------------------------------------------------------------------
// K1: att_raw accumulation (unchanged).
// ---------------------------------------------------------------------------
__global__ __launch_bounds__(256) void k_att(
    const float* __restrict__ x, const float* __restrict__ Wqkv,
    const float* __restrict__ bqkv, float* __restrict__ att_raw)
{
    __shared__ float wq_s[2048], wk_s[2048];
    __shared__ float bq_s[32], bk_s[32];
    __shared__ float pe_s[1600];
    __shared__ float xs_s[3400];
    __shared__ float q_s[1600], k_s[1600];

    const int tid = threadIdx.x;
    const int tblk = blockIdx.x;
    const int h = blockIdx.y, n = blockIdx.z;

    for (int e = tid; e < 2048; e += 256) {
        int cp = e >> 6, c = e & 63;
        wq_s[e] = Wqkv[(h * 32 + cp) * 64 + c];
        wk_s[e] = Wqkv[(96 + h * 32 + cp) * 64 + c];
    }
    if (tid < 32) {
        bq_s[tid] = bqkv[h * 32 + tid];
        bk_s[tid] = bqkv[96 + h * 32 + tid];
    }
    for (int e = tid; e < 1600; e += 256) {
        int c = e / 25, v = e % 25;
        int i = c >> 1;
        float d = expf(-(float)(2 * i) * (9.210340371976184f / 64.0f));
        float a = (float)v * d;
        pe_s[e] = (c & 1) ? cosf(a) : sinf(a);
    }

    float racc[3] = {0.0f, 0.0f, 0.0f};

    for (int chunk = 0; chunk < 8; ++chunk) {
        const int t0 = tblk * 16 + chunk * 2;
        __syncthreads();
        for (int e = tid; e < 3200; e += 256) {
            int c = e / 50, j = e % 50;
            int tl = j / 25, v = j % 25;
            xs_s[j * 68 + c] =
                x[((n * 64 + c) * 128 + t0 + tl) * 25 + v] + pe_s[c * 25 + v];
        }
        __syncthreads();
        for (int e = tid; e < 1600; e += 256) {
            int row = e / 50, j = e % 50;
            float aq = bq_s[row], ak = bk_s[row];
            const float* wqr = &wq_s[row * 64];
            const float* wkr = &wk_s[row * 64];
            const float* xr  = &xs_s[j * 68];
            #pragma unroll 8
            for (int c = 0; c < 64; ++c) {
                float xv = xr[c];
                aq = fmaf(wqr[c], xv, aq);
                ak = fmaf(wkr[c], xv, ak);
            }
            q_s[e] = aq; k_s[e] = ak;
        }
        __syncthreads();
        #pragma unroll
        for (int s = 0; s < 3; ++s) {
            int p = tid + s * 256;
            if (p < 625) {
                int u = p / 25, v = p % 25;
                float acc = racc[s];
                for (int cp = 0; cp < 32; ++cp) {
                    const float* qr = &q_s[cp * 50];
                    const float* kr = &k_s[cp * 50];
                    acc = fmaf(qr[u],      kr[v],      acc);
                    acc = fmaf(qr[25 + u], kr[25 + v], acc);
                }
                racc[s] = acc;
            }
        }
    }

    #pragma unroll
    for (int s = 0; s < 3; ++s) {
        int p = tid + s * 256;
        if (p < 625)
            atomicAdd(&att_raw[(n * 3 + h) * 625 + p], racc[s]);
    }
}

// ---------------------------------------------------------------------------
// K1b: att = tanh(att_raw/4096)*alpha[h] + att0[h,u,v]  (in place)
// ---------------------------------------------------------------------------
__global__ void k_attfin(float* __restrict__ att, const float* __restrict__ alphas,
                         const float* __restrict__ att0s)
{
    int idx = blockIdx.x * 256 + threadIdx.x;
    if (idx >= 64 * 3 * 625) return;
    int nh = idx / 625, p = idx % 625;
    int h = nh % 3;
    float a = att[idx];
    att[idx] = tanhf(a * (1.0f / 4096.0f)) * alphas[h] + att0s[h * 625 + p];
}

// ---------------------------------------------------------------------------
// K2: MFMA implicit-GEMM conv — fully static unroll (no dynamic reg indexing).
// out[o,(t,v)] = sum_{tap,hc} A[tap][o][hc] * yT[t][v+tap][hc]  (+bias)
// ---------------------------------------------------------------------------
__global__ __launch_bounds__(256) void k_conv(
    const float* __restrict__ x, const unsigned short* __restrict__ Abf,
    const float* __restrict__ bout, const float* __restrict__ att,
    float* __restrict__ out)
{
    __shared__ unsigned short yT[22272];   // [t(4)][vv(29)][hc(192)] bf16, swizzled
    __shared__ unsigned short x_sb[6400];  // [c(64)][t(4)][u(25)] bf16
    __shared__ float att_s[1875];          // [h][u][v]

    const int tid = threadIdx.x;
    const int n = blockIdx.y;
    const int t0 = blockIdx.x * 4;

    for (int e = tid; e < 6400; e += 256) {
        int c = e / 100, r = e % 100;
        x_sb[e] = f2us(x[(size_t)(n * 64 + c) * 3200 + t0 * 25 + r]);
    }
    for (int e = tid; e < 1875; e += 256) att_s[e] = att[n * 1875 + e];
    for (int e = tid; e < 3072; e += 256) {
        int t = e / 768, r = e % 768;
        int vi = r / 192, hc = r % 192;
        int vv = (vi < 2) ? vi : (25 + vi);          // {0,1,27,28}
        int phys = (t * 29 + vv) * 192 + (((hc >> 3) ^ (vv & 7)) << 3) + (hc & 7);
        yT[phys] = 0;
    }
    __syncthreads();

    for (int e = tid; e < 9600; e += 256) {
        int col = e / 96, hcp = e % 96;
        int hc = hcp * 2;
        int t = col / 25, v = col % 25;
        int h = hc >> 6, c = hc & 63;
        const unsigned short* xr0 = &x_sb[c * 100 + t * 25];
        const unsigned short* xr1 = xr0 + 100;
        const float* ar = &att_s[h * 625 + v];
        float y0 = 0.0f, y1 = 0.0f;
        #pragma unroll
        for (int u = 0; u < 25; ++u) {
            float a = ar[u * 25];
            y0 = fmaf(us2f(xr0[u]), a, y0);
            y1 = fmaf(us2f(xr1[u]), a, y1);
        }
        int vv = v + 2;
        int phys = (t * 29 + vv) * 192 + (((hc >> 3) ^ (vv & 7)) << 3) + (hc & 7);
        unsigned int pk = (unsigned int)f2us(y0) | ((unsigned int)f2us(y1) << 16);
        *(unsigned int*)&yT[phys] = pk;
    }
    __syncthreads();

    // ---- MFMA GEMM: M=64(o) x N=100(cols) x K=960, all-static ----
    const int lane = tid & 63, wv = tid >> 6;
    const int quad = lane >> 4, l16 = lane & 15;
    const int mgrp = wv >> 1, ngrp = wv & 1;
    const int m0 = mgrp * 32;
    const int nbase = ngrp * 64;

    floatx4 acc00 = {0,0,0,0}, acc01 = {0,0,0,0}, acc02 = {0,0,0,0}, acc03 = {0,0,0,0};
    floatx4 acc10 = {0,0,0,0}, acc11 = {0,0,0,0}, acc12 = {0,0,0,0}, acc13 = {0,0,0,0};

    int col0 = nbase + l16;           if (col0 > 99) col0 = 99;
    int col1 = nbase + 16 + l16;      if (col1 > 99) col1 = 99;
    int col2 = nbase + 32 + l16;      if (col2 > 99) col2 = 99;
    int col3 = nbase + 48 + l16;      if (col3 > 99) col3 = 99;
    const int tc0 = col0 / 25, vc0 = col0 % 25;
    const int tc1 = col1 / 25, vc1 = col1 % 25;
    const int tc2 = col2 / 25, vc2 = col2 % 25;
    const int tc3 = col3 / 25, vc3 = col3 % 25;

    const unsigned short* ap0 = Abf + (m0 + l16) * 192 + quad * 8;
    const unsigned short* ap1 = ap0 + 16 * 192;

    #pragma unroll
    for (int tap = 0; tap < 5; ++tap) {
        const int vv0 = vc0 + tap, vv1 = vc1 + tap, vv2 = vc2 + tap, vv3 = vc3 + tap;
        const int ro0 = (tc0 * 29 + vv0) * 192, vx0 = vv0 & 7;
        const int ro1 = (tc1 * 29 + vv1) * 192, vx1 = vv1 & 7;
        const int ro2 = (tc2 * 29 + vv2) * 192, vx2 = vv2 & 7;
        const int ro3 = (tc3 * 29 + vv3) * 192, vx3 = vv3 & 7;
        #pragma unroll
        for (int kk = 0; kk < 6; ++kk) {
            const int koff = tap * 12288 + kk * 32;
            short8 a0 = *(const short8*)(ap0 + koff);
            short8 a1 = *(const short8*)(ap1 + koff);
            const int hcb = kk * 4 + quad;
            short8 b0 = *(const short8*)&yT[ro0 + ((hcb ^ vx0) << 3)];
            short8 b1 = *(const short8*)&yT[ro1 + ((hcb ^ vx1) << 3)];
            short8 b2 = *(const short8*)&yT[ro2 + ((hcb ^ vx2) << 3)];
            short8 b3 = *(const short8*)&yT[ro3 + ((hcb ^ vx3) << 3)];
            acc00 = __builtin_amdgcn_mfma_f32_16x16x32_bf16(a0, b0, acc00, 0, 0, 0);
            acc10 = __builtin_amdgcn_mfma_f32_16x16x32_bf16(a1, b0, acc10, 0, 0, 0);
            acc01 = __builtin_amdgcn_mfma_f32_16x16x32_bf16(a0, b1, acc01, 0, 0, 0);
            acc11 = __builtin_amdgcn_mfma_f32_16x16x32_bf16(a1, b1, acc11, 0, 0, 0);
            acc02 = __builtin_amdgcn_mfma_f32_16x16x32_bf16(a0, b2, acc02, 0, 0, 0);
            acc12 = __builtin_amdgcn_mfma_f32_16x16x32_bf16(a1, b2, acc12, 0, 0, 0);
            acc03 = __builtin_amdgcn_mfma_f32_16x16x32_bf16(a0, b3, acc03, 0, 0, 0);
            acc13 = __builtin_amdgcn_mfma_f32_16x16x32_bf16(a1, b3, acc13, 0, 0, 0);
        }
    }

    // ---- epilogue: C frag col=lane&15, row=quad*4+reg ----
#define EPI(ACC, MT, NTI)                                                      \
    do {                                                                       \
        int col = nbase + (NTI) * 16 + l16;                                    \
        if (col < 100) {                                                       \
            int t = col / 25, v = col % 25;                                    \
            int ob = m0 + (MT) * 16 + quad * 4;                                \
            float* op = out + (size_t)(n * 64 + ob) * 3200 + (t0 + t) * 25 + v;\
            _Pragma("unroll")                                                  \
            for (int reg = 0; reg < 4; ++reg)                                  \
                op[(size_t)reg * 3200] = ACC[reg] + bout[ob + reg];            \
        }                                                                      \
    } while (0)

    EPI(acc00, 0, 0); EPI(acc01, 0, 1); EPI(acc02, 0, 2); EPI(acc03, 0, 3);
    EPI(acc10, 1, 0); EPI(acc11, 1, 1); EPI(acc12, 1, 2); EPI(acc13, 1, 3);
#undef EPI
}

// ---------------------------------------------------------------------------
// K3: per-channel sum/sumsq of conv output (fp32, staged in d_out).
// ---------------------------------------------------------------------------
__global__ __launch_bounds__(256) void k_stats(const float* __restrict__ conv,
                                               float* __restrict__ stats)
{
    const int o = blockIdx.x;
    const int tid = threadIdx.x;
    float s1 = 0.0f, s2 = 0.0f;
    for (int e = tid; e < 64 * 3200; e += 256) {
        int nn = e / 3200, i = e % 3200;
        float v = conv[(size_t)(nn * 64 + o) * 3200 + i];
        s1 += v; s2 = fmaf(v, v, s2);
    }
    for (int off = 32; off > 0; off >>= 1) {
        s1 += __shfl_down(s1, off);
        s2 += __shfl_down(s2, off);
    }
    __shared__ float r1[4], r2[4];
    int w = tid >> 6;
    if ((tid & 63) == 0) { r1[w] = s1; r2[w] = s2; }
    __syncthreads();
    if (tid == 0) {
        stats[o]      = r1[0] + r1[1] + r1[2] + r1[3];
        stats[64 + o] = r2[0] + r2[1] + r2[2] + r2[3];
    }
}

// ---------------------------------------------------------------------------
// K4: out = leaky_relu( BN(conv) + x ), in place over d_out.
// ---------------------------------------------------------------------------
__global__ void k_final(const float* __restrict__ stats, const float* __restrict__ x,
                        const float* __restrict__ gamma, const float* __restrict__ beta,
                        float* __restrict__ out)
{
    size_t idx = (size_t)blockIdx.x * 256 + threadIdx.x;
    if (idx >= (size_t)13107200) return;
    int o = (int)((idx / 3200) & 63);
    const float inv = 1.0f / 204800.0f;
    float m   = stats[o] * inv;
    float ex2 = stats[64 + o] * inv;
    float var = ex2 - m * m;
    float r = rsqrtf(var + 1e-5f);
    float v = out[idx];
    float val = (v - m) * r * gamma[o] + beta[o] + x[idx];
    val = fmaxf(val, 0.1f * val);
    out[idx] = val;
}

// ---------------------------------------------------------------------------
extern "C" void kernel_launch(void* const* d_in, const int* in_sizes, int n_in,
                              void* d_out, int out_size, void* d_ws, size_t ws_size,
                              hipStream_t stream)
{
    const float* x      = (const float*)d_in[0];
    const float* Wqkv   = (const float*)d_in[1];
    const float* bqkv   = (const float*)d_in[2];
    const float* alphas = (const float*)d_in[3];
    const float* att0s  = (const float*)d_in[4];
    const float* Wout   = (const float*)d_in[5];
    const float* bout   = (const float*)d_in[6];
    const float* gamma  = (const float*)d_in[7];
    const float* beta   = (const float*)d_in[8];
    float* ws  = (float*)d_ws;
    float* out = (float*)d_out;
    unsigned short* Abf = (unsigned short*)(ws + WS_WBF);

    hipMemsetAsync(d_ws, 0, (size_t)120000 * sizeof(float), stream);

    k_wprep <<<240, 256, 0, stream>>>(Wout, Abf);
    k_att   <<<dim3(8, 3, 64), 256, 0, stream>>>(x, Wqkv, bqkv, ws + WS_ATT);
    k_attfin<<<(120000 + 255) / 256, 256, 0, stream>>>(ws + WS_ATT, alphas, att0s);
    k_conv  <<<dim3(32, 64),   256, 0, stream>>>(x, Abf, bout, ws + WS_ATT, out);
    k_stats <<<64,             256, 0, stream>>>(out, ws + WS_STATS);
    k_final <<<51200,          256, 0, stream>>>(ws + WS_STATS, x, gamma, beta, out);
}

// Round 8
// 690.822 us; speedup vs baseline: 5.7676x; 1.3311x over previous
//
#include <hip/hip_runtime.h>
#include <hip/hip_bf16.h>

// Problem constants: N=64, C=64, T=128, V=25, H=3, DQ=32
// Inputs: float32. Output: float32 (compared under bf16-floored threshold).

#define WS_ATT   0         // 120000 floats: att accumulator, then final att
#define WS_STATS 120000    // 128 floats: per-channel sum, sumsq
#define WS_WBF   120128    // 30720 floats-worth = 61440 bf16: Wout as [tap][o][hc]

typedef __attribute__((ext_vector_type(8))) short short8;   // 8 bf16 (4 VGPRs)
typedef __attribute__((ext_vector_type(4))) float floatx4;  // MFMA acc

__device__ __forceinline__ float us2f(unsigned short u) {
    union { unsigned int i; float f; } w; w.i = ((unsigned int)u) << 16; return w.f;
}
__device__ __forceinline__ unsigned short f2us(float f) {
    __hip_bfloat16_raw r = __float2bfloat16(f); return r.x;
}

// ---------------------------------------------------------------------------
// K0: reorder Wout [o=64][I=192][tap=5] fp32 -> Abf [tap][o][hc] bf16 (ws).
// ---------------------------------------------------------------------------
__global__ void k_wprep(const float* __restrict__ Wout, unsigned short* __restrict__ Abf)
{
    int i = blockIdx.x * 256 + threadIdx.x;
    if (i >= 61440) return;
    int tap = i / 12288, rem = i % 12288;
    int o = rem / 192, hc = rem % 192;
    Abf[i] = f2us(Wout[o * 960 + hc * 5 + tap]);
}

// ---------------------------------------------------------------------------
// K1: att_raw accumulation (unchanged from R7).
// ---------------------------------------------------------------------------
__global__ __launch_bounds__(256) void k_att(
    const float* __restrict__ x, const float* __restrict__ Wqkv,
    const float* __restrict__ bqkv, float* __restrict__ att_raw)
{
    __shared__ float wq_s[2048], wk_s[2048];
    __shared__ float bq_s[32], bk_s[32];
    __shared__ float pe_s[1600];
    __shared__ float xs_s[3400];
    __shared__ float q_s[1600], k_s[1600];

    const int tid = threadIdx.x;
    const int tblk = blockIdx.x;
    const int h = blockIdx.y, n = blockIdx.z;

    for (int e = tid; e < 2048; e += 256) {
        int cp = e >> 6, c = e & 63;
        wq_s[e] = Wqkv[(h * 32 + cp) * 64 + c];
        wk_s[e] = Wqkv[(96 + h * 32 + cp) * 64 + c];
    }
    if (tid < 32) {
        bq_s[tid] = bqkv[h * 32 + tid];
        bk_s[tid] = bqkv[96 + h * 32 + tid];
    }
    for (int e = tid; e < 1600; e += 256) {
        int c = e / 25, v = e % 25;
        int i = c >> 1;
        float d = expf(-(float)(2 * i) * (9.210340371976184f / 64.0f));
        float a = (float)v * d;
        pe_s[e] = (c & 1) ? cosf(a) : sinf(a);
    }

    float racc[3] = {0.0f, 0.0f, 0.0f};

    for (int chunk = 0; chunk < 8; ++chunk) {
        const int t0 = tblk * 16 + chunk * 2;
        __syncthreads();
        for (int e = tid; e < 3200; e += 256) {
            int c = e / 50, j = e % 50;
            int tl = j / 25, v = j % 25;
            xs_s[j * 68 + c] =
                x[((n * 64 + c) * 128 + t0 + tl) * 25 + v] + pe_s[c * 25 + v];
        }
        __syncthreads();
        for (int e = tid; e < 1600; e += 256) {
            int row = e / 50, j = e % 50;
            float aq = bq_s[row], ak = bk_s[row];
            const float* wqr = &wq_s[row * 64];
            const float* wkr = &wk_s[row * 64];
            const float* xr  = &xs_s[j * 68];
            #pragma unroll 8
            for (int c = 0; c < 64; ++c) {
                float xv = xr[c];
                aq = fmaf(wqr[c], xv, aq);
                ak = fmaf(wkr[c], xv, ak);
            }
            q_s[e] = aq; k_s[e] = ak;
        }
        __syncthreads();
        #pragma unroll
        for (int s = 0; s < 3; ++s) {
            int p = tid + s * 256;
            if (p < 625) {
                int u = p / 25, v = p % 25;
                float acc = racc[s];
                for (int cp = 0; cp < 32; ++cp) {
                    const float* qr = &q_s[cp * 50];
                    const float* kr = &k_s[cp * 50];
                    acc = fmaf(qr[u],      kr[v],      acc);
                    acc = fmaf(qr[25 + u], kr[25 + v], acc);
                }
                racc[s] = acc;
            }
        }
    }

    #pragma unroll
    for (int s = 0; s < 3; ++s) {
        int p = tid + s * 256;
        if (p < 625)
            atomicAdd(&att_raw[(n * 3 + h) * 625 + p], racc[s]);
    }
}

// ---------------------------------------------------------------------------
// K1b: att = tanh(att_raw/4096)*alpha[h] + att0[h,u,v]  (in place)
// ---------------------------------------------------------------------------
__global__ void k_attfin(float* __restrict__ att, const float* __restrict__ alphas,
                         const float* __restrict__ att0s)
{
    int idx = blockIdx.x * 256 + threadIdx.x;
    if (idx >= 64 * 3 * 625) return;
    int nh = idx / 625, p = idx % 625;
    int h = nh % 3;
    float a = att[idx];
    att[idx] = tanhf(a * (1.0f / 4096.0f)) * alphas[h] + att0s[h * 625 + p];
}

// ---------------------------------------------------------------------------
// K2: MFMA implicit-GEMM conv, 2-frame tile for 4 blocks/CU occupancy.
// out[o,(t,v)] = sum_{tap,hc} A[tap][o][hc] * yT[t][v+tap][hc]  (+bias)
// grid (T/2=64, N=64); 4 waves = (mgrp 2) x (ngrp 2), each 2x2 frags.
// ---------------------------------------------------------------------------
__global__ __launch_bounds__(256, 4) void k_conv(
    const float* __restrict__ x, const unsigned short* __restrict__ Abf,
    const float* __restrict__ bout, const float* __restrict__ att,
    float* __restrict__ out)
{
    __shared__ unsigned short yT[11136];   // [t(2)][vv(29)][hc(192)] bf16, swizzled
    __shared__ unsigned short x_sb[3200];  // [c(64)][t(2)*25+u] bf16
    __shared__ float att_s[1875];          // [h][u][v]

    const int tid = threadIdx.x;
    const int n = blockIdx.y;
    const int t0 = blockIdx.x * 2;

    for (int e = tid; e < 3200; e += 256) {
        int c = e / 50, r = e % 50;
        x_sb[e] = f2us(x[(size_t)(n * 64 + c) * 3200 + t0 * 25 + r]);
    }
    for (int e = tid; e < 1875; e += 256) att_s[e] = att[n * 1875 + e];
    for (int e = tid; e < 1536; e += 256) {
        int t = e / 768, r = e % 768;
        int vi = r / 192, hc = r % 192;
        int vv = (vi < 2) ? vi : (25 + vi);          // {0,1,27,28}
        int phys = (t * 29 + vv) * 192 + (((hc >> 3) ^ (vv & 7)) << 3) + (hc & 7);
        yT[phys] = 0;
    }
    __syncthreads();

    // y[hc][t][v] = sum_u x[c,t,u] att[h,u,v], 2 hc per thread
    for (int e = tid; e < 4800; e += 256) {
        int col = e / 96, hcp = e % 96;
        int hc = hcp * 2;
        int t = col / 25, v = col % 25;
        int h = hc >> 6, c = hc & 63;
        const unsigned short* xr0 = &x_sb[c * 50 + t * 25];
        const unsigned short* xr1 = xr0 + 50;
        const float* ar = &att_s[h * 625 + v];
        float y0 = 0.0f, y1 = 0.0f;
        #pragma unroll
        for (int u = 0; u < 25; ++u) {
            float a = ar[u * 25];
            y0 = fmaf(us2f(xr0[u]), a, y0);
            y1 = fmaf(us2f(xr1[u]), a, y1);
        }
        int vv = v + 2;
        int phys = (t * 29 + vv) * 192 + (((hc >> 3) ^ (vv & 7)) << 3) + (hc & 7);
        unsigned int pk = (unsigned int)f2us(y0) | ((unsigned int)f2us(y1) << 16);
        *(unsigned int*)&yT[phys] = pk;
    }
    __syncthreads();

    // ---- MFMA GEMM: M=64(o) x N=50(cols) x K=960, all-static ----
    const int lane = tid & 63, wv = tid >> 6;
    const int quad = lane >> 4, l16 = lane & 15;
    const int mgrp = wv >> 1, ngrp = wv & 1;
    const int m0 = mgrp * 32;
    const int nbase = ngrp * 32;

    floatx4 acc00 = {0,0,0,0}, acc01 = {0,0,0,0};
    floatx4 acc10 = {0,0,0,0}, acc11 = {0,0,0,0};

    int col0 = nbase + l16;           if (col0 > 49) col0 = 49;
    int col1 = nbase + 16 + l16;      if (col1 > 49) col1 = 49;
    const int tc0 = col0 / 25, vc0 = col0 % 25;
    const int tc1 = col1 / 25, vc1 = col1 % 25;

    const unsigned short* ap0 = Abf + (m0 + l16) * 192 + quad * 8;
    const unsigned short* ap1 = ap0 + 16 * 192;

    #pragma unroll
    for (int tap = 0; tap < 5; ++tap) {
        const int vv0 = vc0 + tap, vv1 = vc1 + tap;
        const int ro0 = (tc0 * 29 + vv0) * 192, vx0 = vv0 & 7;
        const int ro1 = (tc1 * 29 + vv1) * 192, vx1 = vv1 & 7;
        #pragma unroll
        for (int kk = 0; kk < 6; ++kk) {
            const int koff = tap * 12288 + kk * 32;
            short8 a0 = *(const short8*)(ap0 + koff);
            short8 a1 = *(const short8*)(ap1 + koff);
            const int hcb = kk * 4 + quad;
            short8 b0 = *(const short8*)&yT[ro0 + ((hcb ^ vx0) << 3)];
            short8 b1 = *(const short8*)&yT[ro1 + ((hcb ^ vx1) << 3)];
            acc00 = __builtin_amdgcn_mfma_f32_16x16x32_bf16(a0, b0, acc00, 0, 0, 0);
            acc10 = __builtin_amdgcn_mfma_f32_16x16x32_bf16(a1, b0, acc10, 0, 0, 0);
            acc01 = __builtin_amdgcn_mfma_f32_16x16x32_bf16(a0, b1, acc01, 0, 0, 0);
            acc11 = __builtin_amdgcn_mfma_f32_16x16x32_bf16(a1, b1, acc11, 0, 0, 0);
        }
    }

    // ---- epilogue: C frag col=lane&15, row=quad*4+reg ----
#define EPI(ACC, MT, NTI)                                                      \
    do {                                                                       \
        int col = nbase + (NTI) * 16 + l16;                                    \
        if (col < 50) {                                                        \
            int t = col / 25, v = col % 25;                                    \
            int ob = m0 + (MT) * 16 + quad * 4;                                \
            float* op = out + (size_t)(n * 64 + ob) * 3200 + (t0 + t) * 25 + v;\
            _Pragma("unroll")                                                  \
            for (int reg = 0; reg < 4; ++reg)                                  \
                op[(size_t)reg * 3200] = ACC[reg] + bout[ob + reg];            \
        }                                                                      \
    } while (0)

    EPI(acc00, 0, 0); EPI(acc01, 0, 1);
    EPI(acc10, 1, 0); EPI(acc11, 1, 1);
#undef EPI
}

// ---------------------------------------------------------------------------
// K3: per-channel sum/sumsq, parallel over n-slices; atomicAdd to stats.
// grid (8 n-slices, 64 channels).
// ---------------------------------------------------------------------------
__global__ __launch_bounds__(256) void k_stats(const float* __restrict__ conv,
                                               float* __restrict__ stats)
{
    const int o = blockIdx.y;
    const int n0 = blockIdx.x * 8;
    const int tid = threadIdx.x;
    float s1 = 0.0f, s2 = 0.0f;
    for (int e = tid; e < 8 * 3200; e += 256) {
        int nl = e / 3200, i = e % 3200;
        float v = conv[(size_t)((n0 + nl) * 64 + o) * 3200 + i];
        s1 += v; s2 = fmaf(v, v, s2);
    }
    for (int off = 32; off > 0; off >>= 1) {
        s1 += __shfl_down(s1, off);
        s2 += __shfl_down(s2, off);
    }
    __shared__ float r1[4], r2[4];
    int w = tid >> 6;
    if ((tid & 63) == 0) { r1[w] = s1; r2[w] = s2; }
    __syncthreads();
    if (tid == 0) {
        atomicAdd(&stats[o],      r1[0] + r1[1] + r1[2] + r1[3]);
        atomicAdd(&stats[64 + o], r2[0] + r2[1] + r2[2] + r2[3]);
    }
}

// ---------------------------------------------------------------------------
// K4: out = leaky_relu( BN(conv) + x ), in place, float4-vectorized.
// ---------------------------------------------------------------------------
__global__ void k_final(const float* __restrict__ stats, const float4* __restrict__ x4,
                        const float* __restrict__ gamma, const float* __restrict__ beta,
                        float4* __restrict__ out4)
{
    int idx = blockIdx.x * 256 + threadIdx.x;
    if (idx >= 3276800) return;
    int o = (idx / 800) & 63;
    const float inv = 1.0f / 204800.0f;
    float m   = stats[o] * inv;
    float ex2 = stats[64 + o] * inv;
    float var = ex2 - m * m;
    float r = rsqrtf(var + 1e-5f);
    float g = gamma[o], bb = beta[o];
    float4 v = out4[idx];
    float4 xx = x4[idx];
    float4 res;
    float t;
    t = (v.x - m) * r * g + bb + xx.x; res.x = fmaxf(t, 0.1f * t);
    t = (v.y - m) * r * g + bb + xx.y; res.y = fmaxf(t, 0.1f * t);
    t = (v.z - m) * r * g + bb + xx.z; res.z = fmaxf(t, 0.1f * t);
    t = (v.w - m) * r * g + bb + xx.w; res.w = fmaxf(t, 0.1f * t);
    out4[idx] = res;
}

// ---------------------------------------------------------------------------
extern "C" void kernel_launch(void* const* d_in, const int* in_sizes, int n_in,
                              void* d_out, int out_size, void* d_ws, size_t ws_size,
                              hipStream_t stream)
{
    const float* x      = (const float*)d_in[0];
    const float* Wqkv   = (const float*)d_in[1];
    const float* bqkv   = (const float*)d_in[2];
    const float* alphas = (const float*)d_in[3];
    const float* att0s  = (const float*)d_in[4];
    const float* Wout   = (const float*)d_in[5];
    const float* bout   = (const float*)d_in[6];
    const float* gamma  = (const float*)d_in[7];
    const float* beta   = (const float*)d_in[8];
    float* ws  = (float*)d_ws;
    float* out = (float*)d_out;
    unsigned short* Abf = (unsigned short*)(ws + WS_WBF);

    hipMemsetAsync(d_ws, 0, (size_t)(120000 + 128) * sizeof(float), stream);

    k_wprep <<<240, 256, 0, stream>>>(Wout, Abf);
    k_att   <<<dim3(8, 3, 64), 256, 0, stream>>>(x, Wqkv, bqkv, ws + WS_ATT);
    k_attfin<<<(120000 + 255) / 256, 256, 0, stream>>>(ws + WS_ATT, alphas, att0s);
    k_conv  <<<dim3(64, 64),   256, 0, stream>>>(x, Abf, bout, ws + WS_ATT, out);
    k_stats <<<dim3(8, 64),    256, 0, stream>>>(out, ws + WS_STATS);
    k_final <<<12800,          256, 0, stream>>>(ws + WS_STATS, (const float4*)x,
                                                 gamma, beta, (float4*)out);
}